// Round 3
// baseline (292.454 us; speedup 1.0000x reference)
//
#include <hip/hip_runtime.h>
#include <stdint.h>

// Each 64x64 matrix: bf16 planes in LDS, unpadded stride 64, XOR-swizzled:
//   element [r][c] at short-index  r*64 + (((c>>3) ^ (r&7))<<3) + (c&7)
//   R-plane: row-major (MFMA A-fragment = one b128)
//   T-plane: transposed (MFMA B-fragment = one b128)
// 6 fixed plane slots per matrix, 1-periodic schedule; LDS addrs invariant.
//
// ROUND-3 CHANGE: TWO matrices per block (256 blocks x 512 thr, 12 planes,
// 96KB LDS, 1 block/CU). Every inter-barrier round processes both matrices'
// products back-to-back in each wave: two independent read->MFMA->pack->store
// chains per wave let the LDS / MFMA / VALU pipes overlap instead of
// serializing (r2 evidence: pipe-busy sums to ~89% with zero overlap; extra
// waves are phase-locked and don't help).
#define PL 4096  // shorts per plane

typedef unsigned int u32;
typedef unsigned short u16;
typedef float f32x4 __attribute__((ext_vector_type(4)));
typedef short short8 __attribute__((ext_vector_type(8)));

__device__ __forceinline__ u32 prm(u32 a, u32 b, u32 s) {
  return __builtin_amdgcn_perm(a, b, s);
}
__device__ __forceinline__ u32 pk(float f0, float f1) {  // {bf16 f0, bf16 f1}
  return prm(__float_as_uint(f1), __float_as_uint(f0), 0x07060302u);
}
__device__ __forceinline__ float rlo(u32 w) { return __uint_as_float(w << 16); }
__device__ __forceinline__ float rhi(u32 w) {
  return __uint_as_float(w & 0xffff0000u);
}

// Per-thread invariant LDS short-offsets (8-wave split: 1 tile-row band,
// 2 tile-cols per wave). Shared by both matrices (plane base differs).
struct O {
  int ra[2];     // A-frag read [q] (k-half)
  int rb[2][2];  // B-frag read [tj][q]
  int sT[2];     // T-plane store for primary product tile tj
  int sR[2];     // R-plane store for mirror product tile tj
};

struct BF {
  short8 b0[2], b1[2];  // [tj] x k-half
};

__device__ __forceinline__ BF loadB(const u16* __restrict__ BT, const O& o) {
  BF f;
#pragma unroll
  for (int t = 0; t < 2; ++t) {
    f.b0[t] = *(const short8*)(BT + o.rb[t][0]);
    f.b1[t] = *(const short8*)(BT + o.rb[t][1]);
  }
  return f;
}

__device__ __forceinline__ void dot8(short8 a, short8 b, float& part) {
  union {
    short8 s;
    u32 w[4];
  } ua, ub;
  ua.s = a;
  ub.s = b;
#pragma unroll
  for (int w = 0; w < 4; ++w) {
    part = fmaf(rlo(ua.w[w]), rlo(ub.w[w]), part);
    part = fmaf(rhi(ua.w[w]), rhi(ub.w[w]), part);
  }
}

// Dual-matrix C = A @ B (64x64 bf16). 8 waves; wave owns 1 tile-row band x
// 2 tile-cols per matrix. Primary -> T-plane; mirror -> R-plane. WR/WT gate
// dead planes. TR: trace waves {0,2,5,7} have A-frags element-aligned with
// B-frag tile b=wr, so sum R.*T = tr(A*B) free when A=R15,B=T15 (both mats).
// The two matrices' chains are independent -> ILP. Trailing barrier.
template <bool WR, bool WT, bool TR = false>
__device__ __forceinline__ void mm_core2(
    const u16* __restrict__ AR0, const u16* __restrict__ AR1, const BF& bf0,
    const BF& bf1, u16* __restrict__ CR0, u16* __restrict__ CR1,
    u16* __restrict__ CT0, u16* __restrict__ CT1, const O& o,
    float* red = nullptr) {
  short8 a00 = *(const short8*)(AR0 + o.ra[0]);
  short8 a01 = *(const short8*)(AR0 + o.ra[1]);
  short8 a10 = *(const short8*)(AR1 + o.ra[0]);
  short8 a11 = *(const short8*)(AR1 + o.ra[1]);
  if (TR) {
    const int tid = (int)threadIdx.x;
    const int wvv = tid >> 6;
    if ((wvv & 1) == ((wvv >> 2) & 1)) {  // trace waves 0,2,5,7
      const int tjt = (wvv >> 1) & 1;     // wave-uniform; select, not index
      short8 b00 = tjt ? bf0.b0[1] : bf0.b0[0];
      short8 b01 = tjt ? bf0.b1[1] : bf0.b1[0];
      short8 b10 = tjt ? bf1.b0[1] : bf1.b0[0];
      short8 b11 = tjt ? bf1.b1[1] : bf1.b1[0];
      float p0 = 0.0f, p1 = 0.0f;
      dot8(a00, b00, p0);
      dot8(a01, b01, p0);
      dot8(a10, b10, p1);
      dot8(a11, b11, p1);
#pragma unroll
      for (int off = 1; off < 64; off <<= 1) {
        p0 += __shfl_xor(p0, off);
        p1 += __shfl_xor(p1, off);
      }
      if ((tid & 63) == 0) {
        red[wvv >> 1] = p0;
        red[4 + (wvv >> 1)] = p1;
      }
    }
  }
  const f32x4 Z = {0.0f, 0.0f, 0.0f, 0.0f};
#pragma unroll
  for (int tj = 0; tj < 2; ++tj) {
    if (WT) {
      f32x4 u =
          __builtin_amdgcn_mfma_f32_16x16x32_bf16(a00, bf0.b0[tj], Z, 0, 0, 0);
      f32x4 v =
          __builtin_amdgcn_mfma_f32_16x16x32_bf16(a10, bf1.b0[tj], Z, 0, 0, 0);
      u = __builtin_amdgcn_mfma_f32_16x16x32_bf16(a01, bf0.b1[tj], u, 0, 0, 0);
      v = __builtin_amdgcn_mfma_f32_16x16x32_bf16(a11, bf1.b1[tj], v, 0, 0, 0);
      *(uint2*)(CT0 + o.sT[tj]) = make_uint2(pk(u[0], u[1]), pk(u[2], u[3]));
      *(uint2*)(CT1 + o.sT[tj]) = make_uint2(pk(v[0], v[1]), pk(v[2], v[3]));
    }
    if (WR) {
      f32x4 u =
          __builtin_amdgcn_mfma_f32_16x16x32_bf16(bf0.b0[tj], a00, Z, 0, 0, 0);
      f32x4 v =
          __builtin_amdgcn_mfma_f32_16x16x32_bf16(bf1.b0[tj], a10, Z, 0, 0, 0);
      u = __builtin_amdgcn_mfma_f32_16x16x32_bf16(bf0.b1[tj], a01, u, 0, 0, 0);
      v = __builtin_amdgcn_mfma_f32_16x16x32_bf16(bf1.b1[tj], a11, v, 0, 0, 0);
      *(uint2*)(CR0 + o.sR[tj]) = make_uint2(pk(u[0], u[1]), pk(u[2], u[3]));
      *(uint2*)(CR1 + o.sR[tj]) = make_uint2(pk(v[0], v[1]), pk(v[2], v[3]));
    }
  }
  __syncthreads();
}

// One block (512 thr = 8 waves) per 2 batch elements; 1 block/CU.
// Thread owns a 4x2 patch (r0=(tid&15)*4, c0=(tid>>4)*2) per matrix.
//
// 1-periodic 6-slot schedule per matrix, invariant entering each iter:
//   PA=R15, PB=T15, PC=T3  (of current x)
//   f1 m30:(PA,PB)->(PD,PE) [+free trace into red]   f2 m60:(PD,PE)->PF [R]
//   f3 m63:(PF,cC=T3)->PD [T]
//   g: gradprox (alpha from red, T63 from PD); stage m(new x)->(PE=R, PF=T)
//   c1 m2:(PE,PF->cF)->PD [R]  c2 m3:(PD,cF)->(PE=R3, PC=T3)
//   c3 m6:(PE,PC->cC)->(PD,PF) c4 m12:(PD,PF)->PE [R]
//   c5 m15:(PE,cC)->(PA,PB)
__global__ __launch_bounds__(512, 1) void dag_iter_kernel(
    const float* __restrict__ adj, float* __restrict__ out) {
  __shared__ __align__(16) u16 BUF[12 * PL];
  __shared__ float red[8];
  u16* PA0 = BUF;
  u16* PB0 = BUF + PL;
  u16* PC0 = BUF + 2 * PL;
  u16* PD0 = BUF + 3 * PL;
  u16* PE0 = BUF + 4 * PL;
  u16* PF0 = BUF + 5 * PL;
  u16* PA1 = BUF + 6 * PL;
  u16* PB1 = BUF + 7 * PL;
  u16* PC1 = BUF + 8 * PL;
  u16* PD1 = BUF + 9 * PL;
  u16* PE1 = BUF + 10 * PL;
  u16* PF1 = BUF + 11 * PL;

  const int tid = (int)threadIdx.x;
  const int lane = tid & 63;
  const int wv = tid >> 6;
  const int wr = wv >> 1;  // tile-row band 0..3
  const int wc2 = wv & 1;  // tile-col pair 0..1
  const int l15 = lane & 15;
  const int grp = lane >> 4;
  const int l7 = l15 & 7;
  const int r0 = (tid & 15) << 2;
  const int c0 = (tid >> 4) << 1;

  O o;
#pragma unroll
  for (int q = 0; q < 2; ++q) {
    const int koff = (((q << 2) + grp) ^ l7) << 3;
    o.ra[q] = (wr * 16 + l15) * 64 + koff;
#pragma unroll
    for (int t = 0; t < 2; ++t)
      o.rb[t][q] = ((2 * wc2 + t) * 16 + l15) * 64 + koff;
  }
#pragma unroll
  for (int tj = 0; tj < 2; ++tj) {
    const int a = wr;
    const int b = 2 * wc2 + tj;
    o.sT[tj] = (16 * b + l15) * 64 + (((2 * a + (grp >> 1)) ^ l7) << 3) +
               ((grp & 1) << 2);
    o.sR[tj] = (16 * a + l15) * 64 + (((2 * b + (grp >> 1)) ^ l7) << 3) +
               ((grp & 1) << 2);
  }
  int prow[4], pcol[2];
#pragma unroll
  for (int i = 0; i < 4; ++i)
    prow[i] = (r0 + i) * 64 + ((((c0 >> 3) ^ ((r0 + i) & 7))) << 3) + (c0 & 7);
#pragma unroll
  for (int j = 0; j < 2; ++j)
    pcol[j] = (c0 + j) * 64 + ((((r0 >> 3) ^ ((c0 + j) & 7))) << 3) + (r0 & 7);

  float x[2][4][2], sc[2][4][2];
#pragma unroll
  for (int m = 0; m < 2; ++m) {
    const float* src = adj + (size_t)(2 * blockIdx.x + m) * 4096;
#pragma unroll
    for (int i = 0; i < 4; ++i) {
      float2 v = *(const float2*)(src + (r0 + i) * 64 + c0);
      x[m][i][0] = v.x;
      x[m][i][1] = v.y;
      sc[m][i][0] = (v.x > 0.5f) ? v.x : 0.0f;
      sc[m][i][1] = (v.y > 0.5f) ? v.y : 0.0f;
    }
  }
  float alpha[2] = {0.0f, 0.0f};
  BF cC0, cC1;  // register cache of T3's B-frags (c3 -> c5 -> next f3)

  auto prox = [&](float til[2][4][2]) {
#pragma unroll
    for (int m = 0; m < 2; ++m)
#pragma unroll
      for (int i = 0; i < 4; ++i)
#pragma unroll
        for (int j = 0; j < 2; ++j) {
          float ax = fabsf(til[m][i][j]) - 2e-5f;
          float nx = ax > 0.0f ? ax : 0.0f;
          x[m][i][j] = nx > 1.0f ? 1.0f : nx;
        }
  };
  auto stage = [&]() {  // m = I + x.*x/64 -> PE (R-plane), PF (T-plane)
#pragma unroll
    for (int m = 0; m < 2; ++m) {
      u16* RE = m ? PE1 : PE0;
      u16* TF = m ? PF1 : PF0;
      float w[4][2];
#pragma unroll
      for (int i = 0; i < 4; ++i)
#pragma unroll
        for (int j = 0; j < 2; ++j)
          w[i][j] = fmaf(x[m][i][j] * x[m][i][j], 0.015625f,
                         (r0 + i == c0 + j) ? 1.0f : 0.0f);
#pragma unroll
      for (int i = 0; i < 4; ++i) *(u32*)(RE + prow[i]) = pk(w[i][0], w[i][1]);
#pragma unroll
      for (int j = 0; j < 2; ++j)
        *(uint2*)(TF + pcol[j]) =
            make_uint2(pk(w[0][j], w[1][j]), pk(w[2][j], w[3][j]));
    }
    __syncthreads();
  };
  auto chain5 = [&]() {  // sources: PE=R(m), PF=T(m)
    BF cF0 = loadB(PF0, o), cF1 = loadB(PF1, o);
    mm_core2<true, false>(PE0, PE1, cF0, cF1, PD0, PD1, PD0, PD1, o);  // c1
    mm_core2<true, true>(PD0, PD1, cF0, cF1, PE0, PE1, PC0, PC1, o);   // c2
    cC0 = loadB(PC0, o);
    cC1 = loadB(PC1, o);
    mm_core2<true, true>(PE0, PE1, cC0, cC1, PD0, PD1, PF0, PF1, o);  // c3
    BF t0 = loadB(PF0, o), t1 = loadB(PF1, o);
    mm_core2<true, false>(PD0, PD1, t0, t1, PE0, PE1, PE0, PE1, o);   // c4
    mm_core2<true, true>(PE0, PE1, cC0, cC1, PA0, PA1, PB0, PB1, o);  // c5
  };
  auto gradprox = [&]() {  // alpha from red (tr(m30)); T63 in PD
    float til[2][4][2];
#pragma unroll
    for (int m = 0; m < 2; ++m) {
      const u16* TD = m ? PD1 : PD0;
      float tr = red[4 * m] + red[4 * m + 1] + red[4 * m + 2] + red[4 * m + 3];
      alpha[m] = fmaf(0.01f, tr * 0.015625f - 1.0f, alpha[m]);
      const float a2 = alpha[m] * 0.03125f;  // 2*alpha/64
#pragma unroll
      for (int i = 0; i < 4; ++i) {
        u32 w = *(const u32*)(TD + prow[i]);
        float pt[2] = {rlo(w), rhi(w)};
#pragma unroll
        for (int j = 0; j < 2; ++j) {
          float g = fmaf(a2 * x[m][i][j], pt[j], -sc[m][i][j]);
          til[m][i][j] = fmaf(-0.01f, g, x[m][i][j]);
        }
      }
    }
    prox(til);
  };
  auto front = [&]() {
    BF fb0 = loadB(PB0, o), fb1 = loadB(PB1, o);
    mm_core2<true, true, true>(PA0, PA1, fb0, fb1, PD0, PD1, PE0, PE1, o,
                               red);  // f1: m30 (+free trace)
    BF g0 = loadB(PE0, o), g1 = loadB(PE1, o);
    mm_core2<true, false>(PD0, PD1, g0, g1, PF0, PF1, PF0, PF1, o);  // f2: m60
    mm_core2<false, true>(PF0, PF1, cC0, cC1, PD0, PD1, PD0, PD1,
                          o);  // f3: m63 -> T only (PD)
  };

  // ---- iteration 0: alpha == 0 -> grad = -scores ----
  {
    float til[2][4][2];
#pragma unroll
    for (int m = 0; m < 2; ++m)
#pragma unroll
      for (int i = 0; i < 4; ++i)
#pragma unroll
        for (int j = 0; j < 2; ++j)
          til[m][i][j] = fmaf(0.01f, sc[m][i][j], x[m][i][j]);
    prox(til);
    stage();
    chain5();
  }
  // ---- iterations 1..48 ----
  for (int it = 0; it < 48; ++it) {
    front();
    gradprox();
    stage();
    chain5();
  }
  // ---- iteration 49: no trailing stage/chain ----
  front();
  gradprox();

#pragma unroll
  for (int m = 0; m < 2; ++m) {
    float* dst = out + (size_t)(2 * blockIdx.x + m) * 4096;
#pragma unroll
    for (int i = 0; i < 4; ++i) {
      float2 v;
      v.x = (x[m][i][0] > 0.5f) ? x[m][i][0] : 0.0f;
      v.y = (x[m][i][1] > 0.5f) ? x[m][i][1] : 0.0f;
      *(float2*)(dst + (r0 + i) * 64 + c0) = v;
    }
  }
}

extern "C" void kernel_launch(void* const* d_in, const int* in_sizes, int n_in,
                              void* d_out, int out_size, void* d_ws,
                              size_t ws_size, hipStream_t stream) {
  const float* adj = (const float*)d_in[0];
  float* out = (float*)d_out;
  const int nbatch = in_sizes[0] / 4096;  // 512
  dag_iter_kernel<<<nbatch / 2, 512, 0, stream>>>(adj, out);
}